// Round 5
// baseline (426.434 us; speedup 1.0000x reference)
//
#include <hip/hip_runtime.h>

// Problem constants
#define BB 2
#define SS 2048
#define DD 1024
#define HH 8
#define EE 4
#define DHH 128
#define RR (BB*SS)          // 4096 rows

typedef __attribute__((ext_vector_type(8))) short short8;
typedef __attribute__((ext_vector_type(4))) short short4v;
typedef __attribute__((ext_vector_type(4))) float f32x4;

__device__ __forceinline__ float b2f(short x) {
    unsigned u = ((unsigned)(unsigned short)x) << 16;
    return __uint_as_float(u);
}
__device__ __forceinline__ short f2bf(float f) {
    unsigned u = __float_as_uint(f);
    unsigned r = (u + 0x7fffu + ((u >> 16) & 1u)) >> 16;
    return (short)(unsigned short)r;
}

// async global->LDS, 16 bytes per lane (dest = wave-uniform base + lane*16)
__device__ __forceinline__ void gl_lds16(const short* g, short* l) {
    __builtin_amdgcn_global_load_lds(
        (const __attribute__((address_space(1))) unsigned int*)g,
        (__attribute__((address_space(3))) unsigned int*)l,
        16, 0, 0);
}

// ---------------------------------------------------------------------------
// bf16 BT-GEMM body, m97 structure: C[m,n] = alpha * sum_k A[m,k]*B[n,k].
// 128x128 tile, BK=32, 4 waves of 64x64, mfma_f32_16x16x32_bf16.
// Staging via global_load_lds width=16 into LINEAR [128][32] LDS (no pad).
// ---------------------------------------------------------------------------
template <bool BF16_OUT>
__device__ __forceinline__ void gemm16_body(
    short* As, short* Bs,
    const short* __restrict__ A, const short* __restrict__ Bm, void* __restrict__ Cv,
    int Kd, int lda, int ldb, int ldc, float alpha, int bm0, int bn0)
{
    const int t = threadIdx.x;
    const int lane = t & 63, wave = t >> 6;
    const int lm = lane & 15, quad = lane >> 4;
    const int wm = (wave >> 1) * 64, wn = (wave & 1) * 64;
    f32x4 acc[4][4] = {};

    // staging map: thread t -> row (t>>2) in [0,64), col (t&3)*8 of the 32-wide K block
    const int srow = t >> 2, scol = (t & 3) * 8;
    const short* Ag = A + (long)(bm0 + srow) * lda + scol;
    const short* Bg = Bm + (long)(bn0 + srow) * ldb + scol;
    const long ldaH = (long)lda * 64, ldbH = (long)ldb * 64;
    short* Asd = As + srow * 32 + scol;     // LDS dest, row block 0
    short* Bsd = Bs + srow * 32 + scol;

    for (int k0 = 0; k0 < Kd; k0 += 32) {
        __syncthreads();                    // prev compute done before overwrite
        gl_lds16(Ag + k0,        Asd);
        gl_lds16(Ag + k0 + ldaH, Asd + 64 * 32);
        gl_lds16(Bg + k0,        Bsd);
        gl_lds16(Bg + k0 + ldbH, Bsd + 64 * 32);
        __syncthreads();                    // vmcnt(0) drain -> tile ready

        short8 af[4], bf[4];
#pragma unroll
        for (int i = 0; i < 4; i++)
            af[i] = *(const short8*)&As[(wm + i * 16 + lm) * 32 + quad * 8];
#pragma unroll
        for (int j = 0; j < 4; j++)
            bf[j] = *(const short8*)&Bs[(wn + j * 16 + lm) * 32 + quad * 8];
#pragma unroll
        for (int i = 0; i < 4; i++)
#pragma unroll
            for (int j = 0; j < 4; j++)
                acc[i][j] = __builtin_amdgcn_mfma_f32_16x16x32_bf16(
                    af[i], bf[j], acc[i][j], 0, 0, 0);
    }
#pragma unroll
    for (int i = 0; i < 4; i++) {
#pragma unroll
        for (int j = 0; j < 4; j++) {
            int n = bn0 + wn + j * 16 + lm;
#pragma unroll
            for (int r = 0; r < 4; r++) {
                int m = bm0 + wm + i * 16 + quad * 4 + r;
                float v = acc[i][j][r] * alpha;
                if (BF16_OUT) ((short*)Cv)[(long)m * ldc + n] = f2bf(v);
                else          ((float*)Cv)[(long)m * ldc + n] = v;
            }
        }
    }
}

// Generic bf16 wrapper (used for the v_all GEMM)
__global__ __launch_bounds__(256)
void shc_gemm_bt16(const short* __restrict__ A, const short* __restrict__ Bm,
                   void* __restrict__ Cv, int Kd, int lda, int ldb, int ldc,
                   float alpha)
{
    __shared__ short As[128 * 32];
    __shared__ short Bs[128 * 32];
    gemm16_body<true>(As, Bs, A, Bm, Cv, Kd, lda, ldb, ldc, alpha,
                      blockIdx.y * 128, blockIdx.x * 128);
}

// Batched Q/K projection (bf16 inputs): z=0 -> Qs x Wq16 ; z=1 -> Ks x Wk16
__global__ __launch_bounds__(256)
void shc_gemm_qk(const short* __restrict__ Qs, const short* __restrict__ Ks,
                 const short* __restrict__ Wq16, const short* __restrict__ Wk16,
                 short* __restrict__ Qo, short* __restrict__ Ko, float alpha)
{
    __shared__ short As[128 * 32];
    __shared__ short Bs[128 * 32];
    if (blockIdx.z == 0)
        gemm16_body<true>(As, Bs, Qs, Wq16, Qo, 1024, 1024, 1024, 1024,
                          alpha, blockIdx.y * 128, blockIdx.x * 128);
    else
        gemm16_body<true>(As, Bs, Ks, Wk16, Ko, 1024, 1024, 1024, 1024,
                          alpha, blockIdx.y * 128, blockIdx.x * 128);
}

// Final GEMM, split-K=2: z=0 -> out (K 0..2047), z=1 -> P1 (K 2048..4095)
__global__ __launch_bounds__(256)
void shc_gemm_out(const short* __restrict__ X, const short* __restrict__ WoT,
                  float* __restrict__ out, float* __restrict__ P1)
{
    __shared__ short As[128 * 32];
    __shared__ short Bs[128 * 32];
    const int koff = blockIdx.z * 2048;
    float* C = blockIdx.z ? P1 : out;
    gemm16_body<false>(As, Bs, X + koff, WoT + koff, C,
                       2048, 4096, 4096, 1024, 1.0f,
                       blockIdx.y * 128, blockIdx.x * 128);
}

// out += P1  (4M f32)
__global__ __launch_bounds__(256)
void shc_add(float* __restrict__ out, const float* __restrict__ P1)
{
    long i = ((long)blockIdx.x * 256 + threadIdx.x) * 4;
    f32x4 a = *(const f32x4*)(out + i);
    f32x4 b = *(const f32x4*)(P1 + i);
#pragma unroll
    for (int j = 0; j < 4; j++) a[j] += b[j];
    *(f32x4*)(out + i) = a;
}

// f32 -> bf16 bulk conversion, up to 3 arrays selected by blockIdx.z
__global__ __launch_bounds__(256)
void shc_cvt3(const float* __restrict__ a, const float* __restrict__ b,
              const float* __restrict__ c, short* __restrict__ oa,
              short* __restrict__ ob, short* __restrict__ oc)
{
    const float* src = blockIdx.z == 0 ? a : (blockIdx.z == 1 ? b : c);
    short* dst       = blockIdx.z == 0 ? oa : (blockIdx.z == 1 ? ob : oc);
    long i = ((long)blockIdx.x * 256 + threadIdx.x) * 8;
    f32x4 f0 = *(const f32x4*)(src + i);
    f32x4 f1 = *(const f32x4*)(src + i + 4);
    short8 o;
#pragma unroll
    for (int j = 0; j < 4; j++) {
        o[j]     = f2bf(f0[j]);
        o[4 + j] = f2bf(f1[j]);
    }
    *(short8*)(dst + i) = o;
}

// ---------------------------------------------------------------------------
// Router gates, v4: 2 rows per wave, whole block on ONE side so the 4 waves
// stream the same sel rows (L1 reuse); source rows pre-converted to f64 once;
// 5-stage butterfly + combined cross-half stage (bit-identical sum order to
// v3). Lanes 0-31 finish row r0, lanes 32-63 finish row r0+1.
// ---------------------------------------------------------------------------
__global__ __launch_bounds__(256)
void shc_gates4(const float* __restrict__ q_src, const float* __restrict__ k_src,
                const float* __restrict__ sel_v, const float* __restrict__ sel_o,
                float* __restrict__ gv_d, float* __restrict__ go_d)
{
    const int t = threadIdx.x, lane = t & 63, wave = t >> 6;
    const int bid = blockIdx.x;               // 1024
    const int s = bid & 1;                    // whole block same side
    const int r0 = (bid >> 1) * 8 + wave * 2; // rows r0, r0+1
    const float* srcb = s ? q_src : k_src;
    const float* selb = s ? sel_o : sel_v;

    // per-lane 16 contiguous elements of each row, pre-converted to f64
    double S0[16], S1[16];
#pragma unroll
    for (int i = 0; i < 4; i++) {
        f32x4 v0 = *(const f32x4*)(srcb + (long)r0 * 1024 + lane * 16 + i * 4);
        f32x4 v1 = *(const f32x4*)(srcb + (long)(r0 + 1) * 1024 + lane * 16 + i * 4);
#pragma unroll
        for (int j = 0; j < 4; j++) {
            S0[i * 4 + j] = (double)v0[j];
            S1[i * 4 + j] = (double)v1[j];
        }
    }

    float myv = 0.f;
#pragma unroll 2
    for (int o = 0; o < 32; ++o) {
        f32x4 W[4];
#pragma unroll
        for (int i = 0; i < 4; i++)
            W[i] = *(const f32x4*)(selb + o * 1024 + lane * 16 + i * 4);
        double a0 = 0.0, a1 = 0.0;
#pragma unroll
        for (int i = 0; i < 4; i++)
#pragma unroll
            for (int j = 0; j < 4; j++) {
                double w = (double)W[i][j];
                a0 += S0[i * 4 + j] * w;
                a1 += S1[i * 4 + j] * w;
            }
        // butterfly stages 1..16 (both rows), then one combined cross-half stage
        a0 += __shfl_xor(a0, 1);  a1 += __shfl_xor(a1, 1);
        a0 += __shfl_xor(a0, 2);  a1 += __shfl_xor(a1, 2);
        a0 += __shfl_xor(a0, 4);  a1 += __shfl_xor(a1, 4);
        a0 += __shfl_xor(a0, 8);  a1 += __shfl_xor(a1, 8);
        a0 += __shfl_xor(a0, 16); a1 += __shfl_xor(a1, 16);
        double tcross = (lane < 32) ? a1 : a0;
        double u = __shfl_xor(tcross, 32);
        double tot = ((lane < 32) ? a0 : a1) + u;   // == local-half + other-half
        myv = ((lane & 31) == o) ? (float)tot : myv;  // cndmask, static indexing
    }

    // lane = r*32 + o  (r = lane>>5 -> row r0+r, o = lane&31 -> (h=o>>2,e=o&3))
    float sg = 1.f / (1.f + __expf(-myv));
    float g1 = __shfl_xor(sg, 1);
    float g2 = __shfl_xor(sg, 2);
    float g3 = __shfl_xor(sg, 3);
    const int e = lane & 3;
    int rank = 0;
    rank += (g1 > sg) || (g1 == sg && (e ^ 1) < e);
    rank += (g2 > sg) || (g2 == sg && (e ^ 2) < e);
    rank += (g3 > sg) || (g3 == sg && (e ^ 3) < e);
    const long row = r0 + (lane >> 5);
    float* outp = (s ? go_d : gv_d) + row * 32 + (lane & 31);
    *outp = (rank < 2) ? sg : 0.f;
}

// ---------------------------------------------------------------------------
// Merged LDS-tiled weight transposes (coalesced both sides), f32 -> bf16.
// ---------------------------------------------------------------------------
__global__ __launch_bounds__(256)
void shc_transpose_w(const float* __restrict__ Wv, short* __restrict__ WvT,
                     const float* __restrict__ Wo, short* __restrict__ WoT)
{
    __shared__ float Ls[32][33];
    const int t = threadIdx.x;
    const int rr = t >> 3, cc = (t & 7) * 4;
    const int bid = blockIdx.x;
    if (bid < 4096) {
        const int dhT = bid & 3, dT = (bid >> 2) & 31, he = bid >> 7;
        const int d0 = dT * 32, dh0 = dhT * 32;
        f32x4 vin = *(const f32x4*)(Wv + (long)(he * 1024 + d0 + rr) * 128 + dh0 + cc);
#pragma unroll
        for (int j = 0; j < 4; j++) Ls[rr][cc + j] = vin[j];
        __syncthreads();
        short4v ov;
#pragma unroll
        for (int j = 0; j < 4; j++) ov[j] = f2bf(Ls[cc + j][rr]);
        *(short4v*)(WvT + (long)(he * 128 + dh0 + rr) * 1024 + d0 + cc) = ov;
    } else {
        const int b2 = bid - 4096;              // 4096 = kT(128) * oT(32)
        const int oT = b2 & 31, kT = b2 >> 5;
        const int k0 = kT * 32, o0 = oT * 32;
        f32x4 vin = *(const f32x4*)(Wo + (long)(k0 + rr) * 1024 + o0 + cc);
#pragma unroll
        for (int j = 0; j < 4; j++) Ls[rr][cc + j] = vin[j];
        __syncthreads();
        short4v ov;
#pragma unroll
        for (int j = 0; j < 4; j++) ov[j] = f2bf(Ls[cc + j][rr]);
        *(short4v*)(WoT + (long)(o0 + rr) * 4096 + k0 + cc) = ov;
    }
}

// ---------------------------------------------------------------------------
// Gated V combine + transpose: Vt[b][h][dh][s] = bf16(sum_e gv * v_all)
// ---------------------------------------------------------------------------
__global__ __launch_bounds__(256)
void shc_combine_vt(const short* __restrict__ v_all, const float* __restrict__ gv_d,
                    short* __restrict__ Vt)
{
    __shared__ short Ls[64 * 136];
    const int t = threadIdx.x;
    const int blk = blockIdx.x;            // 512 = B*H*(S/64)
    const int st = blk & 31, h = (blk >> 5) & 7, b = blk >> 8;
    const int s0 = st * 64;
    const int sl = t >> 2, dh0 = (t & 3) * 32;
    const long row = (long)(b * SS) + s0 + sl;
    const float* g = gv_d + row * 32 + h * 4;
    float g0 = g[0], g1 = g[1], g2 = g[2], g3 = g[3];
    const short* va = v_all + row * 4096 + h * 512;
#pragma unroll
    for (int j = 0; j < 4; j++) {
        int dh = dh0 + j * 8;
        short8 e0 = *(const short8*)(va + 0 * 128 + dh);
        short8 e1 = *(const short8*)(va + 1 * 128 + dh);
        short8 e2 = *(const short8*)(va + 2 * 128 + dh);
        short8 e3 = *(const short8*)(va + 3 * 128 + dh);
        short8 outv;
#pragma unroll
        for (int i = 0; i < 8; i++)
            outv[i] = f2bf(g0 * b2f(e0[i]) + g1 * b2f(e1[i])
                         + g2 * b2f(e2[i]) + g3 * b2f(e3[i]));
        *(short8*)&Ls[sl * 136 + dh] = outv;
    }
    __syncthreads();
    const int dh = t >> 1, sc0 = (t & 1) * 32;
    short* op = Vt + ((long)(b * HH + h) * DHH + dh) * SS + s0 + sc0;
#pragma unroll
    for (int j = 0; j < 4; j++) {
        short8 ov;
#pragma unroll
        for (int i = 0; i < 8; i++)
            ov[i] = Ls[(sc0 + j * 8 + i) * 136 + dh];
        *(short8*)(op + j * 8) = ov;
    }
}

// ---------------------------------------------------------------------------
// MFMA flash attention v3: 32 q-rows per wave (128 q per block, 256 blocks).
// - halves per-q LDS read traffic: each Ks/Vs fragment feeds TWO q sub-blocks
// - K/V staged via global_load_lds width=16 with PRE-SWIZZLED global source
//   and linear LDS dest (rule 21); reads use the XOR swizzle
// - softmax folded to exp2: Q,K pre-scaled by sqrt(log2 e), acc init
//   -10*log2(e); p = exp2(acc) = native v_exp_f32
// - fused O-expert gating epilogue (two 64-row passes over shared Of)
// ---------------------------------------------------------------------------
#define NEG10L2E -14.426950408889634f
__global__ __launch_bounds__(256, 1)
void shc_attn_mfma(const short* __restrict__ Q, const short* __restrict__ Kg,
                   const short* __restrict__ Vt, const float* __restrict__ go_d,
                   short* __restrict__ X)
{
    __shared__ __align__(16) char smem[49152];
    short* Ks = (short*)smem;                  // [64][128] shorts, swizzled (16384 B)
    short* Vs = (short*)(smem + 16384);        // [128][64] shorts, swizzled (16384 B)
    const int t = threadIdx.x;
    const int lane = t & 63, wave = t >> 6;
    const int lm = lane & 15, quad = lane >> 4;
    short* Pw = (short*)(smem + 32768) + wave * 2048;  // per-wave [32][64] (4096 B)
    const int blk = blockIdx.x;        // 256 = B*H*(S/128)
    const int qt = blk & 15, h = (blk >> 4) & 7, b = blk >> 7;
    const int q0 = qt * 128 + wave * 32;
    const short* Qb = Q + ((long)(b * SS) + q0) * DD + h * DHH;
    const short* Kb = Kg + (long)(b * SS) * DD + h * DHH;
    const short* Vb = Vt + (long)(b * HH + h) * DHH * SS;

    short8 af[2][4];
#pragma unroll
    for (int qb = 0; qb < 2; qb++)
#pragma unroll
        for (int c = 0; c < 4; c++)
            af[qb][c] = *(const short8*)(Qb + (long)(qb * 16 + lm) * DD + c * 32 + quad * 8);

    f32x4 o_acc[2][8] = {};
    float l_lane[2][4] = {};

    const int lmswz = (lm & 7) << 3;           // read-side swizzle (rows ≡ lm mod 8)
    const int w16 = wave * 16, w32 = wave * 32;

    // staging source addressing (pre-swizzled global, linear LDS dest)
    const int rK = lane >> 4;                          // 0..3
    const int colKe = ((lane & 15) * 8) ^ (rK << 3);   // i even
    const int colKo = colKe ^ 32;                      // i odd (swz += 4<<3)
    const int rV = lane >> 3;                          // 0..7
    const int colV = ((lane & 7) * 8) ^ (rV << 3);

    for (int kt = 0; kt < SS / 64; ++kt) {
        __syncthreads();                       // prev tile's reads done
#pragma unroll
        for (int i = 0; i < 4; i++) {
            const short* kg = Kb + (long)(kt * 64 + w16 + i * 4 + rK) * DD
                              + ((i & 1) ? colKo : colKe);
            gl_lds16(kg, Ks + (w16 + i * 4) * 128);
            const short* vg = Vb + (long)(w32 + i * 8 + rV) * SS + kt * 64 + colV;
            gl_lds16(vg, Vs + (w32 + i * 8) * 64);
        }
        __syncthreads();                       // vmcnt(0) drain -> tile ready

        // QK^T, both q sub-blocks share each Ks fragment read
#pragma unroll
        for (int f = 0; f < 4; f++) {
            f32x4 a0 = {NEG10L2E, NEG10L2E, NEG10L2E, NEG10L2E};
            f32x4 a1 = a0;
#pragma unroll
            for (int c = 0; c < 4; c++) {
                short8 bf = *(const short8*)&Ks[(f * 16 + lm) * 128
                                                + ((c * 32 + quad * 8) ^ lmswz)];
                a0 = __builtin_amdgcn_mfma_f32_16x16x32_bf16(af[0][c], bf, a0, 0, 0, 0);
                a1 = __builtin_amdgcn_mfma_f32_16x16x32_bf16(af[1][c], bf, a1, 0, 0, 0);
            }
#pragma unroll
            for (int r = 0; r < 4; r++) {
                const int pr = quad * 4 + r;
                const int psw = (pr & 7) << 3;
                float p0 = exp2f(a0[r]);
                l_lane[0][r] += p0;
                Pw[pr * 64 + ((f * 16 + lm) ^ psw)] = f2bf(p0);
                float p1 = exp2f(a1[r]);
                l_lane[1][r] += p1;
                Pw[(16 + pr) * 64 + ((f * 16 + lm) ^ psw)] = f2bf(p1);
            }
        }

        short8 ap[2][2];
#pragma unroll
        for (int qb = 0; qb < 2; qb++) {
            ap[qb][0] = *(const short8*)&Pw[(qb * 16 + lm) * 64 + ((quad * 8) ^ lmswz)];
            ap[qb][1] = *(const short8*)&Pw[(qb * 16 + lm) * 64 + ((32 + quad * 8) ^ lmswz)];
        }
#pragma unroll
        for (int d = 0; d < 8; d++) {
            short8 bv0 = *(const short8*)&Vs[(d * 16 + lm) * 64 + ((quad * 8) ^ lmswz)];
            short8 bv1 = *(const short8*)&Vs[(d * 16 + lm) * 64 + ((32 + quad * 8) ^ lmswz)];
            o_acc[0][d] = __builtin_amdgcn_mfma_f32_16x16x32_bf16(ap[0][0], bv0, o_acc[0][d], 0, 0, 0);
            o_acc[0][d] = __builtin_amdgcn_mfma_f32_16x16x32_bf16(ap[0][1], bv1, o_acc[0][d], 0, 0, 0);
            o_acc[1][d] = __builtin_amdgcn_mfma_f32_16x16x32_bf16(ap[1][0], bv0, o_acc[1][d], 0, 0, 0);
            o_acc[1][d] = __builtin_amdgcn_mfma_f32_16x16x32_bf16(ap[1][1], bv1, o_acc[1][d], 0, 0, 0);
        }
    }

    float inv_r[2][4];
#pragma unroll
    for (int qb = 0; qb < 2; qb++)
#pragma unroll
        for (int r = 0; r < 4; r++) {
            float l = l_lane[qb][r];
            l += __shfl_xor(l, 1);
            l += __shfl_xor(l, 2);
            l += __shfl_xor(l, 4);
            l += __shfl_xor(l, 8);
            inv_r[qb][r] = 1.f / l;
        }

    // Epilogue: two 64-row passes (qb halves) through shared Of
    float* Of = (float*)smem;            // 64 rows * 132 f32 = 33792 B
#pragma unroll
    for (int hb = 0; hb < 2; hb++) {
        __syncthreads();                 // Ks/Vs/Pw reads (or prev pass) done
#pragma unroll
        for (int r = 0; r < 4; r++) {
#pragma unroll
            for (int d = 0; d < 8; d++)
                Of[(w16 + quad * 4 + r) * 132 + d * 16 + lm] = o_acc[hb][d][r] * inv_r[hb][r];
        }
        __syncthreads();
        const int xr = t >> 2, xc0 = (t & 3) * 8;
        const long grow = (long)(b * SS) + qt * 128 + (xr >> 4) * 32 + hb * 16 + (xr & 15);
        const float* go4 = go_d + grow * 32 + h * 4;
        float gg[4] = {go4[0], go4[1], go4[2], go4[3]};
        short* Xp = X + grow * 4096 + h * 512;
#pragma unroll
        for (int e = 0; e < 4; e++) {
#pragma unroll
            for (int j = 0; j < 4; j++) {
                int c = xc0 + 32 * j;
                f32x4 f0 = *(const f32x4*)&Of[xr * 132 + c];
                f32x4 f1 = *(const f32x4*)&Of[xr * 132 + c + 4];
                short8 s;
#pragma unroll
                for (int i = 0; i < 4; i++) {
                    s[i]     = f2bf(f0[i] * gg[e]);
                    s[4 + i] = f2bf(f1[i] * gg[e]);
                }
                *(short8*)(Xp + e * 128 + c) = s;
            }
        }
    }
}

// ---------------------------------------------------------------------------
extern "C" void kernel_launch(void* const* d_in, const int* in_sizes, int n_in,
                              void* d_out, int out_size, void* d_ws, size_t ws_size,
                              hipStream_t stream)
{
    const float* q_src = (const float*)d_in[0];
    const float* k_src = (const float*)d_in[1];
    const float* v_src = (const float*)d_in[2];
    const float* Wq    = (const float*)d_in[3];
    const float* Wk    = (const float*)d_in[4];
    const float* Wv    = (const float*)d_in[5];
    const float* Wo    = (const float*)d_in[6];
    const float* sel_v = (const float*)d_in[7];
    const float* sel_o = (const float*)d_in[8];
    float* out = (float*)d_out;
    char* ws = (char*)d_ws;

    // Workspace layout (bytes), with lifetime-disjoint aliases:
    //   Qs16/Ks16 live in P1's region  (P1 written at launch 7, reads of Qs/Ks end at launch 2)
    //   Vs16 lives in Vtg's region     (Vtg written at launch 5, Vs16 last read launch 4)
    //   Wq16/Wk16 live in Vall's head  (Vall written at launch 4, reads end at launch 2)
    short* Qb16 = (short*)(ws + 0);            // [4096][1024] bf16  8.4 MB
    short* Kb16 = (short*)(ws + 8388608);      // [4096][1024] bf16  8.4 MB
    short* Vtg  = (short*)(ws + 16777216);     // [16][128][2048] bf16 8.4 MB
    short* Vs16 = (short*)(ws + 16777216);     // alias Vtg (dead before combine)
    short* Vall = (short*)(ws + 25165824);     // [4096][4096] bf16 33.5 MB
    short* X    = (short*)(ws + 25165824);     // alias Vall
    short* Wq16 = (short*)(ws + 25165824);     // alias Vall head (dead before v_all GEMM)
    short* Wk16 = (short*)(ws + 27262976);     // alias Vall +2.1MB
    float* P1   = (float*)(ws + 58720256);     // [4096][1024] f32 16.8 MB
    short* Qs16 = (short*)(ws + 58720256);     // alias P1 (dead before gemm_out)
    short* Ks16 = (short*)(ws + 67108864);     // alias P1 +8.4MB
    short* WvT  = (short*)(ws + 75497472);     // [4096][1024] bf16 8.4 MB
    short* WoT  = (short*)(ws + 83886080);     // [1024][4096] bf16 8.4 MB
    float* GVd  = (float*)(ws + 92274688);     // [4096][32] f32
    float* GOd  = (float*)(ws + 92798976);     // [4096][32] f32
    // total ~93.3 MB

    // DH^-0.25 * sqrt(log2 e): folds softmax exp -> exp2 (native v_exp_f32)
    const float s_scale = 0.29730177875068026f * 1.2011224087864498f;

    dim3 blk(256);
    // 0. f32 -> bf16 conversions (q/k/v sources; Wq/Wk)
    shc_cvt3<<<dim3(2048, 1, 3), blk, 0, stream>>>(q_src, k_src, v_src, Qs16, Ks16, Vs16);
    shc_cvt3<<<dim3(512, 1, 2), blk, 0, stream>>>(Wq, Wk, Wk, Wq16, Wk16, Wk16);
    // 1. Q and K projections, batched in one launch
    shc_gemm_qk<<<dim3(8, 32, 2), blk, 0, stream>>>(Qs16, Ks16, Wq16, Wk16, Qb16, Kb16, s_scale);
    // 2. Router gates v4 (2 rows/wave, block-per-side for L1 W reuse)
    shc_gates4<<<1024, blk, 0, stream>>>(q_src, k_src, sel_v, sel_o, GVd, GOd);
    // 3. merged weight transposes (Wv + Wo)
    shc_transpose_w<<<8192, blk, 0, stream>>>(Wv, WvT, Wo, WoT);
    // 4. v_all GEMM, gated combine + transpose
    shc_gemm_bt16<<<dim3(32, 32), blk, 0, stream>>>(Vs16, WvT, Vall, 1024, 1024, 1024, 4096, 1.0f);
    shc_combine_vt<<<512, blk, 0, stream>>>(Vall, GVd, Vtg);
    // 5. MFMA flash attention v3 (32q/wave, gl_lds staging), fused O-gating -> X
    shc_attn_mfma<<<256, blk, 0, stream>>>(Qb16, Kb16, Vtg, GOd, X);
    // 6. final GEMM, split-K=2 (512 blocks), then partial reduce
    shc_gemm_out<<<dim3(8, 32, 2), blk, 0, stream>>>(X, WoT, out, P1);
    shc_add<<<4096, blk, 0, stream>>>(out, P1);
}

// Round 6
// 419.894 us; speedup vs baseline: 1.0156x; 1.0156x over previous
//
#include <hip/hip_runtime.h>

// Problem constants
#define BB 2
#define SS 2048
#define DD 1024
#define HH 8
#define EE 4
#define DHH 128
#define RR (BB*SS)          // 4096 rows

typedef __attribute__((ext_vector_type(8))) short short8;
typedef __attribute__((ext_vector_type(4))) short short4v;
typedef __attribute__((ext_vector_type(4))) float f32x4;

__device__ __forceinline__ float b2f(short x) {
    unsigned u = ((unsigned)(unsigned short)x) << 16;
    return __uint_as_float(u);
}
__device__ __forceinline__ short f2bf(float f) {
    unsigned u = __float_as_uint(f);
    unsigned r = (u + 0x7fffu + ((u >> 16) & 1u)) >> 16;
    return (short)(unsigned short)r;
}

// async global->LDS, 16 bytes per lane (dest = wave-uniform base + lane*16)
__device__ __forceinline__ void gl_lds16(const short* g, short* l) {
    __builtin_amdgcn_global_load_lds(
        (const __attribute__((address_space(1))) unsigned int*)g,
        (__attribute__((address_space(3))) unsigned int*)l,
        16, 0, 0);
}

// ---------------------------------------------------------------------------
// bf16 BT-GEMM body, m97 structure: C[m,n] = alpha * sum_k A[m,k]*B[n,k].
// 128x128 tile, BK=32, 4 waves of 64x64, mfma_f32_16x16x32_bf16.
// Staging via global_load_lds width=16 into LINEAR [128][32] LDS (no pad).
// ---------------------------------------------------------------------------
template <bool BF16_OUT>
__device__ __forceinline__ void gemm16_body(
    short* As, short* Bs,
    const short* __restrict__ A, const short* __restrict__ Bm, void* __restrict__ Cv,
    int Kd, int lda, int ldb, int ldc, float alpha, int bm0, int bn0)
{
    const int t = threadIdx.x;
    const int lane = t & 63, wave = t >> 6;
    const int lm = lane & 15, quad = lane >> 4;
    const int wm = (wave >> 1) * 64, wn = (wave & 1) * 64;
    f32x4 acc[4][4] = {};

    // staging map: thread t -> row (t>>2) in [0,64), col (t&3)*8 of the 32-wide K block
    const int srow = t >> 2, scol = (t & 3) * 8;
    const short* Ag = A + (long)(bm0 + srow) * lda + scol;
    const short* Bg = Bm + (long)(bn0 + srow) * ldb + scol;
    const long ldaH = (long)lda * 64, ldbH = (long)ldb * 64;
    short* Asd = As + srow * 32 + scol;     // LDS dest, row block 0
    short* Bsd = Bs + srow * 32 + scol;

    for (int k0 = 0; k0 < Kd; k0 += 32) {
        __syncthreads();                    // prev compute done before overwrite
        gl_lds16(Ag + k0,        Asd);
        gl_lds16(Ag + k0 + ldaH, Asd + 64 * 32);
        gl_lds16(Bg + k0,        Bsd);
        gl_lds16(Bg + k0 + ldbH, Bsd + 64 * 32);
        __syncthreads();                    // vmcnt(0) drain -> tile ready

        short8 af[4], bf[4];
#pragma unroll
        for (int i = 0; i < 4; i++)
            af[i] = *(const short8*)&As[(wm + i * 16 + lm) * 32 + quad * 8];
#pragma unroll
        for (int j = 0; j < 4; j++)
            bf[j] = *(const short8*)&Bs[(wn + j * 16 + lm) * 32 + quad * 8];
#pragma unroll
        for (int i = 0; i < 4; i++)
#pragma unroll
            for (int j = 0; j < 4; j++)
                acc[i][j] = __builtin_amdgcn_mfma_f32_16x16x32_bf16(
                    af[i], bf[j], acc[i][j], 0, 0, 0);
    }
#pragma unroll
    for (int i = 0; i < 4; i++) {
#pragma unroll
        for (int j = 0; j < 4; j++) {
            int n = bn0 + wn + j * 16 + lm;
#pragma unroll
            for (int r = 0; r < 4; r++) {
                int m = bm0 + wm + i * 16 + quad * 4 + r;
                float v = acc[i][j][r] * alpha;
                if (BF16_OUT) ((short*)Cv)[(long)m * ldc + n] = f2bf(v);
                else          ((float*)Cv)[(long)m * ldc + n] = v;
            }
        }
    }
}

// Generic bf16 wrapper (used for the v_all GEMM)
__global__ __launch_bounds__(256)
void shc_gemm_bt16(const short* __restrict__ A, const short* __restrict__ Bm,
                   void* __restrict__ Cv, int Kd, int lda, int ldb, int ldc,
                   float alpha)
{
    __shared__ short As[128 * 32];
    __shared__ short Bs[128 * 32];
    gemm16_body<true>(As, Bs, A, Bm, Cv, Kd, lda, ldb, ldc, alpha,
                      blockIdx.y * 128, blockIdx.x * 128);
}

// Batched Q/K projection (bf16 inputs): z=0 -> Qs x Wq16 ; z=1 -> Ks x Wk16
__global__ __launch_bounds__(256)
void shc_gemm_qk(const short* __restrict__ Qs, const short* __restrict__ Ks,
                 const short* __restrict__ Wq16, const short* __restrict__ Wk16,
                 short* __restrict__ Qo, short* __restrict__ Ko, float alpha)
{
    __shared__ short As[128 * 32];
    __shared__ short Bs[128 * 32];
    if (blockIdx.z == 0)
        gemm16_body<true>(As, Bs, Qs, Wq16, Qo, 1024, 1024, 1024, 1024,
                          alpha, blockIdx.y * 128, blockIdx.x * 128);
    else
        gemm16_body<true>(As, Bs, Ks, Wk16, Ko, 1024, 1024, 1024, 1024,
                          alpha, blockIdx.y * 128, blockIdx.x * 128);
}

// Final GEMM, split-K=2: z=0 -> out (K 0..2047), z=1 -> P1 (K 2048..4095)
__global__ __launch_bounds__(256)
void shc_gemm_out(const short* __restrict__ X, const short* __restrict__ WoT,
                  float* __restrict__ out, float* __restrict__ P1)
{
    __shared__ short As[128 * 32];
    __shared__ short Bs[128 * 32];
    const int koff = blockIdx.z * 2048;
    float* C = blockIdx.z ? P1 : out;
    gemm16_body<false>(As, Bs, X + koff, WoT + koff, C,
                       2048, 4096, 4096, 1024, 1.0f,
                       blockIdx.y * 128, blockIdx.x * 128);
}

// out += P1  (4M f32)
__global__ __launch_bounds__(256)
void shc_add(float* __restrict__ out, const float* __restrict__ P1)
{
    long i = ((long)blockIdx.x * 256 + threadIdx.x) * 4;
    f32x4 a = *(const f32x4*)(out + i);
    f32x4 b = *(const f32x4*)(P1 + i);
#pragma unroll
    for (int j = 0; j < 4; j++) a[j] += b[j];
    *(f32x4*)(out + i) = a;
}

// f32 -> bf16 bulk conversion, up to 3 arrays selected by blockIdx.z
__global__ __launch_bounds__(256)
void shc_cvt3(const float* __restrict__ a, const float* __restrict__ b,
              const float* __restrict__ c, short* __restrict__ oa,
              short* __restrict__ ob, short* __restrict__ oc)
{
    const float* src = blockIdx.z == 0 ? a : (blockIdx.z == 1 ? b : c);
    short* dst       = blockIdx.z == 0 ? oa : (blockIdx.z == 1 ? ob : oc);
    long i = ((long)blockIdx.x * 256 + threadIdx.x) * 8;
    f32x4 f0 = *(const f32x4*)(src + i);
    f32x4 f1 = *(const f32x4*)(src + i + 4);
    short8 o;
#pragma unroll
    for (int j = 0; j < 4; j++) {
        o[j]     = f2bf(f0[j]);
        o[4 + j] = f2bf(f1[j]);
    }
    *(short8*)(dst + i) = o;
}

// ---------------------------------------------------------------------------
// Router gates, v4: 2 rows per wave, whole block on ONE side so the 4 waves
// stream the same sel rows (L1 reuse); source rows pre-converted to f64 once;
// 5-stage butterfly + combined cross-half stage (bit-identical sum order to
// v3). Lanes 0-31 finish row r0, lanes 32-63 finish row r0+1.
// ---------------------------------------------------------------------------
__global__ __launch_bounds__(256)
void shc_gates4(const float* __restrict__ q_src, const float* __restrict__ k_src,
                const float* __restrict__ sel_v, const float* __restrict__ sel_o,
                float* __restrict__ gv_d, float* __restrict__ go_d)
{
    const int t = threadIdx.x, lane = t & 63, wave = t >> 6;
    const int bid = blockIdx.x;               // 1024
    const int s = bid & 1;                    // whole block same side
    const int r0 = (bid >> 1) * 8 + wave * 2; // rows r0, r0+1
    const float* srcb = s ? q_src : k_src;
    const float* selb = s ? sel_o : sel_v;

    // per-lane 16 contiguous elements of each row, pre-converted to f64
    double S0[16], S1[16];
#pragma unroll
    for (int i = 0; i < 4; i++) {
        f32x4 v0 = *(const f32x4*)(srcb + (long)r0 * 1024 + lane * 16 + i * 4);
        f32x4 v1 = *(const f32x4*)(srcb + (long)(r0 + 1) * 1024 + lane * 16 + i * 4);
#pragma unroll
        for (int j = 0; j < 4; j++) {
            S0[i * 4 + j] = (double)v0[j];
            S1[i * 4 + j] = (double)v1[j];
        }
    }

    float myv = 0.f;
#pragma unroll 2
    for (int o = 0; o < 32; ++o) {
        f32x4 W[4];
#pragma unroll
        for (int i = 0; i < 4; i++)
            W[i] = *(const f32x4*)(selb + o * 1024 + lane * 16 + i * 4);
        double a0 = 0.0, a1 = 0.0;
#pragma unroll
        for (int i = 0; i < 4; i++)
#pragma unroll
            for (int j = 0; j < 4; j++) {
                double w = (double)W[i][j];
                a0 += S0[i * 4 + j] * w;
                a1 += S1[i * 4 + j] * w;
            }
        // butterfly stages 1..16 (both rows), then one combined cross-half stage
        a0 += __shfl_xor(a0, 1);  a1 += __shfl_xor(a1, 1);
        a0 += __shfl_xor(a0, 2);  a1 += __shfl_xor(a1, 2);
        a0 += __shfl_xor(a0, 4);  a1 += __shfl_xor(a1, 4);
        a0 += __shfl_xor(a0, 8);  a1 += __shfl_xor(a1, 8);
        a0 += __shfl_xor(a0, 16); a1 += __shfl_xor(a1, 16);
        double tcross = (lane < 32) ? a1 : a0;
        double u = __shfl_xor(tcross, 32);
        double tot = ((lane < 32) ? a0 : a1) + u;   // == local-half + other-half
        myv = ((lane & 31) == o) ? (float)tot : myv;  // cndmask, static indexing
    }

    // lane = r*32 + o  (r = lane>>5 -> row r0+r, o = lane&31 -> (h=o>>2,e=o&3))
    float sg = 1.f / (1.f + __expf(-myv));
    float g1 = __shfl_xor(sg, 1);
    float g2 = __shfl_xor(sg, 2);
    float g3 = __shfl_xor(sg, 3);
    const int e = lane & 3;
    int rank = 0;
    rank += (g1 > sg) || (g1 == sg && (e ^ 1) < e);
    rank += (g2 > sg) || (g2 == sg && (e ^ 2) < e);
    rank += (g3 > sg) || (g3 == sg && (e ^ 3) < e);
    const long row = r0 + (lane >> 5);
    float* outp = (s ? go_d : gv_d) + row * 32 + (lane & 31);
    *outp = (rank < 2) ? sg : 0.f;
}

// ---------------------------------------------------------------------------
// Merged LDS-tiled weight transposes (coalesced both sides), f32 -> bf16.
// ---------------------------------------------------------------------------
__global__ __launch_bounds__(256)
void shc_transpose_w(const float* __restrict__ Wv, short* __restrict__ WvT,
                     const float* __restrict__ Wo, short* __restrict__ WoT)
{
    __shared__ float Ls[32][33];
    const int t = threadIdx.x;
    const int rr = t >> 3, cc = (t & 7) * 4;
    const int bid = blockIdx.x;
    if (bid < 4096) {
        const int dhT = bid & 3, dT = (bid >> 2) & 31, he = bid >> 7;
        const int d0 = dT * 32, dh0 = dhT * 32;
        f32x4 vin = *(const f32x4*)(Wv + (long)(he * 1024 + d0 + rr) * 128 + dh0 + cc);
#pragma unroll
        for (int j = 0; j < 4; j++) Ls[rr][cc + j] = vin[j];
        __syncthreads();
        short4v ov;
#pragma unroll
        for (int j = 0; j < 4; j++) ov[j] = f2bf(Ls[cc + j][rr]);
        *(short4v*)(WvT + (long)(he * 128 + dh0 + rr) * 1024 + d0 + cc) = ov;
    } else {
        const int b2 = bid - 4096;              // 4096 = kT(128) * oT(32)
        const int oT = b2 & 31, kT = b2 >> 5;
        const int k0 = kT * 32, o0 = oT * 32;
        f32x4 vin = *(const f32x4*)(Wo + (long)(k0 + rr) * 1024 + o0 + cc);
#pragma unroll
        for (int j = 0; j < 4; j++) Ls[rr][cc + j] = vin[j];
        __syncthreads();
        short4v ov;
#pragma unroll
        for (int j = 0; j < 4; j++) ov[j] = f2bf(Ls[cc + j][rr]);
        *(short4v*)(WoT + (long)(o0 + rr) * 4096 + k0 + cc) = ov;
    }
}

// ---------------------------------------------------------------------------
// Gated V combine + transpose: Vt[b][h][dh][s] = bf16(sum_e gv * v_all)
// ---------------------------------------------------------------------------
__global__ __launch_bounds__(256)
void shc_combine_vt(const short* __restrict__ v_all, const float* __restrict__ gv_d,
                    short* __restrict__ Vt)
{
    __shared__ short Ls[64 * 136];
    const int t = threadIdx.x;
    const int blk = blockIdx.x;            // 512 = B*H*(S/64)
    const int st = blk & 31, h = (blk >> 5) & 7, b = blk >> 8;
    const int s0 = st * 64;
    const int sl = t >> 2, dh0 = (t & 3) * 32;
    const long row = (long)(b * SS) + s0 + sl;
    const float* g = gv_d + row * 32 + h * 4;
    float g0 = g[0], g1 = g[1], g2 = g[2], g3 = g[3];
    const short* va = v_all + row * 4096 + h * 512;
#pragma unroll
    for (int j = 0; j < 4; j++) {
        int dh = dh0 + j * 8;
        short8 e0 = *(const short8*)(va + 0 * 128 + dh);
        short8 e1 = *(const short8*)(va + 1 * 128 + dh);
        short8 e2 = *(const short8*)(va + 2 * 128 + dh);
        short8 e3 = *(const short8*)(va + 3 * 128 + dh);
        short8 outv;
#pragma unroll
        for (int i = 0; i < 8; i++)
            outv[i] = f2bf(g0 * b2f(e0[i]) + g1 * b2f(e1[i])
                         + g2 * b2f(e2[i]) + g3 * b2f(e3[i]));
        *(short8*)&Ls[sl * 136 + dh] = outv;
    }
    __syncthreads();
    const int dh = t >> 1, sc0 = (t & 1) * 32;
    short* op = Vt + ((long)(b * HH + h) * DHH + dh) * SS + s0 + sc0;
#pragma unroll
    for (int j = 0; j < 4; j++) {
        short8 ov;
#pragma unroll
        for (int i = 0; i < 8; i++)
            ov[i] = Ls[(sc0 + j * 8 + i) * 136 + dh];
        *(short8*)(op + j * 8) = ov;
    }
}

// ---------------------------------------------------------------------------
// MFMA flash attention v4: 2-wave blocks (128 thr), 64 q/block (32 q/wave),
// grid 512 -> 2 blocks/CU; DOUBLE-BUFFERED gl_lds K/V staging (one barrier
// per kt, prefetch hides under compute); pre-swizzled global source + linear
// LDS dest (rule 21), XOR swizzle on reads; exp2 softmax (scale folded).
// LDS: K0 16K | V0 16K | K1 16K | V1 16K | Pw 2x4K = 72 KB.
// ---------------------------------------------------------------------------
#define NEG10L2E -14.426950408889634f
__global__ __launch_bounds__(128, 1)
void shc_attn_mfma(const short* __restrict__ Q, const short* __restrict__ Kg,
                   const short* __restrict__ Vt, const float* __restrict__ go_d,
                   short* __restrict__ X)
{
    __shared__ __align__(16) char smem[73728];
    const int t = threadIdx.x;
    const int lane = t & 63, wave = t >> 6;
    const int lm = lane & 15, quad = lane >> 4;
    short* Pw = (short*)(smem + 65536) + wave * 2048;  // per-wave [32][64]
    const int blk = blockIdx.x;        // 512 = B*H*(S/64)
    const int qt = blk & 31, h = (blk >> 5) & 7, b = blk >> 8;
    const int q0 = qt * 64 + wave * 32;
    const short* Qb = Q + ((long)(b * SS) + q0) * DD + h * DHH;
    const short* Kb = Kg + (long)(b * SS) * DD + h * DHH;
    const short* Vb = Vt + (long)(b * HH + h) * DHH * SS;

    short8 af[2][4];
#pragma unroll
    for (int qb = 0; qb < 2; qb++)
#pragma unroll
        for (int c = 0; c < 4; c++)
            af[qb][c] = *(const short8*)(Qb + (long)(qb * 16 + lm) * DD + c * 32 + quad * 8);

    f32x4 o_acc[2][8] = {};
    float l_lane[2][4] = {};

    const int lmswz = (lm & 7) << 3;           // read-side swizzle (rows ≡ lm mod 8)
    const int w32 = wave * 32, w64 = wave * 64;

    // staging source addressing (pre-swizzled global, linear LDS dest)
    const int rK = lane >> 4;                          // 0..3 (4 K rows / gl_lds)
    const int colK = ((lane & 15) * 8) ^ (rK << 3);    // i even; odd adds ^32
    const int rV = lane >> 3;                          // 0..7 (8 V rows / gl_lds)
    const int colV = ((lane & 7) * 8) ^ (rV << 3);

    // stage K rows [w32, w32+32), V rows [w64, w64+64) of tile ktile into buffer bo
    auto STAGE = [&](int ktile, int bo) {
        short* KsD = (short*)(smem + bo);
        short* VsD = (short*)(smem + 16384 + bo);
#pragma unroll
        for (int i = 0; i < 8; i++) {
            const short* kg = Kb + (long)(ktile * 64 + w32 + i * 4 + rK) * DD
                              + (colK ^ ((i & 1) << 5));
            gl_lds16(kg, KsD + (w32 + i * 4) * 128);
            const short* vg = Vb + (long)(w64 + i * 8 + rV) * SS + ktile * 64 + colV;
            gl_lds16(vg, VsD + (w64 + i * 8) * 64);
        }
    };

    STAGE(0, 0);
    for (int kt = 0; kt < SS / 64; ++kt) {
        const int bo = (kt & 1) << 15;         // 0 / 32768
        __syncthreads();                       // drains this tile's stage; prev reads done
        if (kt < SS / 64 - 1) STAGE(kt + 1, bo ^ 32768);
        const short* Ks = (const short*)(smem + bo);
        const short* Vs = (const short*)(smem + 16384 + bo);

        // QK^T, both q sub-blocks share each Ks fragment read
#pragma unroll
        for (int f = 0; f < 4; f++) {
            f32x4 a0 = {NEG10L2E, NEG10L2E, NEG10L2E, NEG10L2E};
            f32x4 a1 = a0;
#pragma unroll
            for (int c = 0; c < 4; c++) {
                short8 bf = *(const short8*)&Ks[(f * 16 + lm) * 128
                                                + ((c * 32 + quad * 8) ^ lmswz)];
                a0 = __builtin_amdgcn_mfma_f32_16x16x32_bf16(af[0][c], bf, a0, 0, 0, 0);
                a1 = __builtin_amdgcn_mfma_f32_16x16x32_bf16(af[1][c], bf, a1, 0, 0, 0);
            }
#pragma unroll
            for (int r = 0; r < 4; r++) {
                const int pr = quad * 4 + r;
                const int psw = (pr & 7) << 3;
                float p0 = exp2f(a0[r]);
                l_lane[0][r] += p0;
                Pw[pr * 64 + ((f * 16 + lm) ^ psw)] = f2bf(p0);
                float p1 = exp2f(a1[r]);
                l_lane[1][r] += p1;
                Pw[(16 + pr) * 64 + ((f * 16 + lm) ^ psw)] = f2bf(p1);
            }
        }

        short8 ap[2][2];
#pragma unroll
        for (int qb = 0; qb < 2; qb++) {
            ap[qb][0] = *(const short8*)&Pw[(qb * 16 + lm) * 64 + ((quad * 8) ^ lmswz)];
            ap[qb][1] = *(const short8*)&Pw[(qb * 16 + lm) * 64 + ((32 + quad * 8) ^ lmswz)];
        }
#pragma unroll
        for (int d = 0; d < 8; d++) {
            short8 bv0 = *(const short8*)&Vs[(d * 16 + lm) * 64 + ((quad * 8) ^ lmswz)];
            short8 bv1 = *(const short8*)&Vs[(d * 16 + lm) * 64 + ((32 + quad * 8) ^ lmswz)];
            o_acc[0][d] = __builtin_amdgcn_mfma_f32_16x16x32_bf16(ap[0][0], bv0, o_acc[0][d], 0, 0, 0);
            o_acc[0][d] = __builtin_amdgcn_mfma_f32_16x16x32_bf16(ap[0][1], bv1, o_acc[0][d], 0, 0, 0);
            o_acc[1][d] = __builtin_amdgcn_mfma_f32_16x16x32_bf16(ap[1][0], bv0, o_acc[1][d], 0, 0, 0);
            o_acc[1][d] = __builtin_amdgcn_mfma_f32_16x16x32_bf16(ap[1][1], bv1, o_acc[1][d], 0, 0, 0);
        }
    }

    float inv_r[2][4];
#pragma unroll
    for (int qb = 0; qb < 2; qb++)
#pragma unroll
        for (int r = 0; r < 4; r++) {
            float l = l_lane[qb][r];
            l += __shfl_xor(l, 1);
            l += __shfl_xor(l, 2);
            l += __shfl_xor(l, 4);
            l += __shfl_xor(l, 8);
            inv_r[qb][r] = 1.f / l;
        }

    // Epilogue: single 64-row pass through shared Of (rows = block q rows)
    float* Of = (float*)smem;            // 64 rows * 132 f32 = 33792 B
    __syncthreads();                     // all waves done with Ks/Vs/Pw
#pragma unroll
    for (int qb = 0; qb < 2; qb++)
#pragma unroll
        for (int r = 0; r < 4; r++) {
#pragma unroll
            for (int d = 0; d < 8; d++)
                Of[(w32 + qb * 16 + quad * 4 + r) * 132 + d * 16 + lm] =
                    o_acc[qb][d][r] * inv_r[qb][r];
        }
    __syncthreads();
    const int xr = t >> 1, xc0 = (t & 1) * 8;
    const long grow = (long)(b * SS) + qt * 64 + xr;
    const float* go4 = go_d + grow * 32 + h * 4;
    float gg[4] = {go4[0], go4[1], go4[2], go4[3]};
    short* Xp = X + grow * 4096 + h * 512;
#pragma unroll
    for (int e = 0; e < 4; e++) {
#pragma unroll
        for (int j = 0; j < 8; j++) {
            int c = xc0 + 16 * j;
            f32x4 f0 = *(const f32x4*)&Of[xr * 132 + c];
            f32x4 f1 = *(const f32x4*)&Of[xr * 132 + c + 4];
            short8 s;
#pragma unroll
            for (int i = 0; i < 4; i++) {
                s[i]     = f2bf(f0[i] * gg[e]);
                s[4 + i] = f2bf(f1[i] * gg[e]);
            }
            *(short8*)(Xp + e * 128 + c) = s;
        }
    }
}

// ---------------------------------------------------------------------------
extern "C" void kernel_launch(void* const* d_in, const int* in_sizes, int n_in,
                              void* d_out, int out_size, void* d_ws, size_t ws_size,
                              hipStream_t stream)
{
    const float* q_src = (const float*)d_in[0];
    const float* k_src = (const float*)d_in[1];
    const float* v_src = (const float*)d_in[2];
    const float* Wq    = (const float*)d_in[3];
    const float* Wk    = (const float*)d_in[4];
    const float* Wv    = (const float*)d_in[5];
    const float* Wo    = (const float*)d_in[6];
    const float* sel_v = (const float*)d_in[7];
    const float* sel_o = (const float*)d_in[8];
    float* out = (float*)d_out;
    char* ws = (char*)d_ws;

    // Workspace layout (bytes), with lifetime-disjoint aliases:
    //   Qs16/Ks16 live in P1's region  (P1 written at launch 7, reads of Qs/Ks end at launch 2)
    //   Vs16 lives in Vtg's region     (Vtg written at launch 5, Vs16 last read launch 4)
    //   Wq16/Wk16 live in Vall's head  (Vall written at launch 4, reads end at launch 2)
    short* Qb16 = (short*)(ws + 0);            // [4096][1024] bf16  8.4 MB
    short* Kb16 = (short*)(ws + 8388608);      // [4096][1024] bf16  8.4 MB
    short* Vtg  = (short*)(ws + 16777216);     // [16][128][2048] bf16 8.4 MB
    short* Vs16 = (short*)(ws + 16777216);     // alias Vtg (dead before combine)
    short* Vall = (short*)(ws + 25165824);     // [4096][4096] bf16 33.5 MB
    short* X    = (short*)(ws + 25165824);     // alias Vall
    short* Wq16 = (short*)(ws + 25165824);     // alias Vall head (dead before v_all GEMM)
    short* Wk16 = (short*)(ws + 27262976);     // alias Vall +2.1MB
    float* P1   = (float*)(ws + 58720256);     // [4096][1024] f32 16.8 MB
    short* Qs16 = (short*)(ws + 58720256);     // alias P1 (dead before gemm_out)
    short* Ks16 = (short*)(ws + 67108864);     // alias P1 +8.4MB
    short* WvT  = (short*)(ws + 75497472);     // [4096][1024] bf16 8.4 MB
    short* WoT  = (short*)(ws + 83886080);     // [1024][4096] bf16 8.4 MB
    float* GVd  = (float*)(ws + 92274688);     // [4096][32] f32
    float* GOd  = (float*)(ws + 92798976);     // [4096][32] f32
    // total ~93.3 MB

    // DH^-0.25 * sqrt(log2 e): folds softmax exp -> exp2 (native v_exp_f32)
    const float s_scale = 0.29730177875068026f * 1.2011224087864498f;

    dim3 blk(256);
    // 0. f32 -> bf16 conversions (q/k/v sources; Wq/Wk)
    shc_cvt3<<<dim3(2048, 1, 3), blk, 0, stream>>>(q_src, k_src, v_src, Qs16, Ks16, Vs16);
    shc_cvt3<<<dim3(512, 1, 2), blk, 0, stream>>>(Wq, Wk, Wk, Wq16, Wk16, Wk16);
    // 1. Q and K projections, batched in one launch
    shc_gemm_qk<<<dim3(8, 32, 2), blk, 0, stream>>>(Qs16, Ks16, Wq16, Wk16, Qb16, Kb16, s_scale);
    // 2. Router gates v4 (2 rows/wave, block-per-side for L1 W reuse)
    shc_gates4<<<1024, blk, 0, stream>>>(q_src, k_src, sel_v, sel_o, GVd, GOd);
    // 3. merged weight transposes (Wv + Wo)
    shc_transpose_w<<<8192, blk, 0, stream>>>(Wv, WvT, Wo, WoT);
    // 4. v_all GEMM, gated combine + transpose
    shc_gemm_bt16<<<dim3(32, 32), blk, 0, stream>>>(Vs16, WvT, Vall, 1024, 1024, 1024, 4096, 1.0f);
    shc_combine_vt<<<512, blk, 0, stream>>>(Vall, GVd, Vtg);
    // 5. MFMA flash attention v4 (2-wave blocks, double-buffered staging)
    shc_attn_mfma<<<512, dim3(128), 0, stream>>>(Qb16, Kb16, Vtg, GOd, X);
    // 6. final GEMM, split-K=2 (512 blocks), then partial reduce
    shc_gemm_out<<<dim3(8, 32, 2), blk, 0, stream>>>(X, WoT, out, P1);
    shc_add<<<4096, blk, 0, stream>>>(out, P1);
}

// Round 8
// 407.374 us; speedup vs baseline: 1.0468x; 1.0307x over previous
//
#include <hip/hip_runtime.h>

// Problem constants
#define BB 2
#define SS 2048
#define DD 1024
#define HH 8
#define EE 4
#define DHH 128
#define RR (BB*SS)          // 4096 rows

typedef __attribute__((ext_vector_type(8))) short short8;
typedef __attribute__((ext_vector_type(4))) short short4v;
typedef __attribute__((ext_vector_type(4))) float f32x4;

__device__ __forceinline__ float b2f(short x) {
    unsigned u = ((unsigned)(unsigned short)x) << 16;
    return __uint_as_float(u);
}
__device__ __forceinline__ short f2bf(float f) {
    unsigned u = __float_as_uint(f);
    unsigned r = (u + 0x7fffu + ((u >> 16) & 1u)) >> 16;
    return (short)(unsigned short)r;
}

// async global->LDS, 16 bytes per lane (dest = wave-uniform base + lane*16)
__device__ __forceinline__ void gl_lds16(const short* g, short* l) {
    __builtin_amdgcn_global_load_lds(
        (const __attribute__((address_space(1))) unsigned int*)g,
        (__attribute__((address_space(3))) unsigned int*)l,
        16, 0, 0);
}

// ---------------------------------------------------------------------------
// bf16 BT-GEMM body, m97 structure: C[m,n] = alpha * sum_k A[m,k]*B[n,k].
// 128x128 tile, BK=32, 4 waves of 64x64, mfma_f32_16x16x32_bf16.
// Staging via global_load_lds width=16 into LINEAR [128][32] LDS (no pad).
// ---------------------------------------------------------------------------
template <bool BF16_OUT>
__device__ __forceinline__ void gemm16_body(
    short* As, short* Bs,
    const short* __restrict__ A, const short* __restrict__ Bm, void* __restrict__ Cv,
    int Kd, int lda, int ldb, int ldc, float alpha, int bm0, int bn0)
{
    const int t = threadIdx.x;
    const int lane = t & 63, wave = t >> 6;
    const int lm = lane & 15, quad = lane >> 4;
    const int wm = (wave >> 1) * 64, wn = (wave & 1) * 64;
    f32x4 acc[4][4] = {};

    // staging map: thread t -> row (t>>2) in [0,64), col (t&3)*8 of the 32-wide K block
    const int srow = t >> 2, scol = (t & 3) * 8;
    const short* Ag = A + (long)(bm0 + srow) * lda + scol;
    const short* Bg = Bm + (long)(bn0 + srow) * ldb + scol;
    const long ldaH = (long)lda * 64, ldbH = (long)ldb * 64;
    short* Asd = As + srow * 32 + scol;     // LDS dest, row block 0
    short* Bsd = Bs + srow * 32 + scol;

    for (int k0 = 0; k0 < Kd; k0 += 32) {
        __syncthreads();                    // prev compute done before overwrite
        gl_lds16(Ag + k0,        Asd);
        gl_lds16(Ag + k0 + ldaH, Asd + 64 * 32);
        gl_lds16(Bg + k0,        Bsd);
        gl_lds16(Bg + k0 + ldbH, Bsd + 64 * 32);
        __syncthreads();                    // vmcnt(0) drain -> tile ready

        short8 af[4], bf[4];
#pragma unroll
        for (int i = 0; i < 4; i++)
            af[i] = *(const short8*)&As[(wm + i * 16 + lm) * 32 + quad * 8];
#pragma unroll
        for (int j = 0; j < 4; j++)
            bf[j] = *(const short8*)&Bs[(wn + j * 16 + lm) * 32 + quad * 8];
#pragma unroll
        for (int i = 0; i < 4; i++)
#pragma unroll
            for (int j = 0; j < 4; j++)
                acc[i][j] = __builtin_amdgcn_mfma_f32_16x16x32_bf16(
                    af[i], bf[j], acc[i][j], 0, 0, 0);
    }
#pragma unroll
    for (int i = 0; i < 4; i++) {
#pragma unroll
        for (int j = 0; j < 4; j++) {
            int n = bn0 + wn + j * 16 + lm;
#pragma unroll
            for (int r = 0; r < 4; r++) {
                int m = bm0 + wm + i * 16 + quad * 4 + r;
                float v = acc[i][j][r] * alpha;
                if (BF16_OUT) ((short*)Cv)[(long)m * ldc + n] = f2bf(v);
                else          ((float*)Cv)[(long)m * ldc + n] = v;
            }
        }
    }
}

// Generic bf16 wrapper (used for the v_all GEMM)
__global__ __launch_bounds__(256)
void shc_gemm_bt16(const short* __restrict__ A, const short* __restrict__ Bm,
                   void* __restrict__ Cv, int Kd, int lda, int ldb, int ldc,
                   float alpha)
{
    __shared__ short As[128 * 32];
    __shared__ short Bs[128 * 32];
    gemm16_body<true>(As, Bs, A, Bm, Cv, Kd, lda, ldb, ldc, alpha,
                      blockIdx.y * 128, blockIdx.x * 128);
}

// Batched Q/K projection (bf16 inputs): z=0 -> Qs x Wq16 ; z=1 -> Ks x Wk16
__global__ __launch_bounds__(256)
void shc_gemm_qk(const short* __restrict__ Qs, const short* __restrict__ Ks,
                 const short* __restrict__ Wq16, const short* __restrict__ Wk16,
                 short* __restrict__ Qo, short* __restrict__ Ko, float alpha)
{
    __shared__ short As[128 * 32];
    __shared__ short Bs[128 * 32];
    if (blockIdx.z == 0)
        gemm16_body<true>(As, Bs, Qs, Wq16, Qo, 1024, 1024, 1024, 1024,
                          alpha, blockIdx.y * 128, blockIdx.x * 128);
    else
        gemm16_body<true>(As, Bs, Ks, Wk16, Ko, 1024, 1024, 1024, 1024,
                          alpha, blockIdx.y * 128, blockIdx.x * 128);
}

// Final GEMM, split-K=2: z=0 -> out (K 0..2047), z=1 -> P1 (K 2048..4095)
__global__ __launch_bounds__(256)
void shc_gemm_out(const short* __restrict__ X, const short* __restrict__ WoT,
                  float* __restrict__ out, float* __restrict__ P1)
{
    __shared__ short As[128 * 32];
    __shared__ short Bs[128 * 32];
    const int koff = blockIdx.z * 2048;
    float* C = blockIdx.z ? P1 : out;
    gemm16_body<false>(As, Bs, X + koff, WoT + koff, C,
                       2048, 4096, 4096, 1024, 1.0f,
                       blockIdx.y * 128, blockIdx.x * 128);
}

// out += P1  (4M f32)
__global__ __launch_bounds__(256)
void shc_add(float* __restrict__ out, const float* __restrict__ P1)
{
    long i = ((long)blockIdx.x * 256 + threadIdx.x) * 4;
    f32x4 a = *(const f32x4*)(out + i);
    f32x4 b = *(const f32x4*)(P1 + i);
#pragma unroll
    for (int j = 0; j < 4; j++) a[j] += b[j];
    *(f32x4*)(out + i) = a;
}

// f32 -> bf16 bulk conversion, up to 3 arrays selected by blockIdx.z
__global__ __launch_bounds__(256)
void shc_cvt3(const float* __restrict__ a, const float* __restrict__ b,
              const float* __restrict__ c, short* __restrict__ oa,
              short* __restrict__ ob, short* __restrict__ oc)
{
    const float* src = blockIdx.z == 0 ? a : (blockIdx.z == 1 ? b : c);
    short* dst       = blockIdx.z == 0 ? oa : (blockIdx.z == 1 ? ob : oc);
    long i = ((long)blockIdx.x * 256 + threadIdx.x) * 8;
    f32x4 f0 = *(const f32x4*)(src + i);
    f32x4 f1 = *(const f32x4*)(src + i + 4);
    short8 o;
#pragma unroll
    for (int j = 0; j < 4; j++) {
        o[j]     = f2bf(f0[j]);
        o[4 + j] = f2bf(f1[j]);
    }
    *(short8*)(dst + i) = o;
}

// ---------------------------------------------------------------------------
// Router gates, v4: 2 rows per wave, whole block on ONE side so the 4 waves
// stream the same sel rows (L1 reuse); source rows pre-converted to f64 once;
// 5-stage butterfly + combined cross-half stage (bit-identical sum order to
// v3). Lanes 0-31 finish row r0, lanes 32-63 finish row r0+1.
// ---------------------------------------------------------------------------
__global__ __launch_bounds__(256)
void shc_gates4(const float* __restrict__ q_src, const float* __restrict__ k_src,
                const float* __restrict__ sel_v, const float* __restrict__ sel_o,
                float* __restrict__ gv_d, float* __restrict__ go_d)
{
    const int t = threadIdx.x, lane = t & 63, wave = t >> 6;
    const int bid = blockIdx.x;               // 1024
    const int s = bid & 1;                    // whole block same side
    const int r0 = (bid >> 1) * 8 + wave * 2; // rows r0, r0+1
    const float* srcb = s ? q_src : k_src;
    const float* selb = s ? sel_o : sel_v;

    // per-lane 16 contiguous elements of each row, pre-converted to f64
    double S0[16], S1[16];
#pragma unroll
    for (int i = 0; i < 4; i++) {
        f32x4 v0 = *(const f32x4*)(srcb + (long)r0 * 1024 + lane * 16 + i * 4);
        f32x4 v1 = *(const f32x4*)(srcb + (long)(r0 + 1) * 1024 + lane * 16 + i * 4);
#pragma unroll
        for (int j = 0; j < 4; j++) {
            S0[i * 4 + j] = (double)v0[j];
            S1[i * 4 + j] = (double)v1[j];
        }
    }

    float myv = 0.f;
#pragma unroll 2
    for (int o = 0; o < 32; ++o) {
        f32x4 W[4];
#pragma unroll
        for (int i = 0; i < 4; i++)
            W[i] = *(const f32x4*)(selb + o * 1024 + lane * 16 + i * 4);
        double a0 = 0.0, a1 = 0.0;
#pragma unroll
        for (int i = 0; i < 4; i++)
#pragma unroll
            for (int j = 0; j < 4; j++) {
                double w = (double)W[i][j];
                a0 += S0[i * 4 + j] * w;
                a1 += S1[i * 4 + j] * w;
            }
        // butterfly stages 1..16 (both rows), then one combined cross-half stage
        a0 += __shfl_xor(a0, 1);  a1 += __shfl_xor(a1, 1);
        a0 += __shfl_xor(a0, 2);  a1 += __shfl_xor(a1, 2);
        a0 += __shfl_xor(a0, 4);  a1 += __shfl_xor(a1, 4);
        a0 += __shfl_xor(a0, 8);  a1 += __shfl_xor(a1, 8);
        a0 += __shfl_xor(a0, 16); a1 += __shfl_xor(a1, 16);
        double tcross = (lane < 32) ? a1 : a0;
        double u = __shfl_xor(tcross, 32);
        double tot = ((lane < 32) ? a0 : a1) + u;   // == local-half + other-half
        myv = ((lane & 31) == o) ? (float)tot : myv;  // cndmask, static indexing
    }

    // lane = r*32 + o  (r = lane>>5 -> row r0+r, o = lane&31 -> (h=o>>2,e=o&3))
    float sg = 1.f / (1.f + __expf(-myv));
    float g1 = __shfl_xor(sg, 1);
    float g2 = __shfl_xor(sg, 2);
    float g3 = __shfl_xor(sg, 3);
    const int e = lane & 3;
    int rank = 0;
    rank += (g1 > sg) || (g1 == sg && (e ^ 1) < e);
    rank += (g2 > sg) || (g2 == sg && (e ^ 2) < e);
    rank += (g3 > sg) || (g3 == sg && (e ^ 3) < e);
    const long row = r0 + (lane >> 5);
    float* outp = (s ? go_d : gv_d) + row * 32 + (lane & 31);
    *outp = (rank < 2) ? sg : 0.f;
}

// ---------------------------------------------------------------------------
// Merged LDS-tiled weight transposes (coalesced both sides), f32 -> bf16.
// ---------------------------------------------------------------------------
__global__ __launch_bounds__(256)
void shc_transpose_w(const float* __restrict__ Wv, short* __restrict__ WvT,
                     const float* __restrict__ Wo, short* __restrict__ WoT)
{
    __shared__ float Ls[32][33];
    const int t = threadIdx.x;
    const int rr = t >> 3, cc = (t & 7) * 4;
    const int bid = blockIdx.x;
    if (bid < 4096) {
        const int dhT = bid & 3, dT = (bid >> 2) & 31, he = bid >> 7;
        const int d0 = dT * 32, dh0 = dhT * 32;
        f32x4 vin = *(const f32x4*)(Wv + (long)(he * 1024 + d0 + rr) * 128 + dh0 + cc);
#pragma unroll
        for (int j = 0; j < 4; j++) Ls[rr][cc + j] = vin[j];
        __syncthreads();
        short4v ov;
#pragma unroll
        for (int j = 0; j < 4; j++) ov[j] = f2bf(Ls[cc + j][rr]);
        *(short4v*)(WvT + (long)(he * 128 + dh0 + rr) * 1024 + d0 + cc) = ov;
    } else {
        const int b2 = bid - 4096;              // 4096 = kT(128) * oT(32)
        const int oT = b2 & 31, kT = b2 >> 5;
        const int k0 = kT * 32, o0 = oT * 32;
        f32x4 vin = *(const f32x4*)(Wo + (long)(k0 + rr) * 1024 + o0 + cc);
#pragma unroll
        for (int j = 0; j < 4; j++) Ls[rr][cc + j] = vin[j];
        __syncthreads();
        short4v ov;
#pragma unroll
        for (int j = 0; j < 4; j++) ov[j] = f2bf(Ls[cc + j][rr]);
        *(short4v*)(WoT + (long)(o0 + rr) * 4096 + k0 + cc) = ov;
    }
}

// ---------------------------------------------------------------------------
// Gated V combine + transpose: Vt[b][h][dh][s] = bf16(sum_e gv * v_all)
// ---------------------------------------------------------------------------
__global__ __launch_bounds__(256)
void shc_combine_vt(const short* __restrict__ v_all, const float* __restrict__ gv_d,
                    short* __restrict__ Vt)
{
    __shared__ short Ls[64 * 136];
    const int t = threadIdx.x;
    const int blk = blockIdx.x;            // 512 = B*H*(S/64)
    const int st = blk & 31, h = (blk >> 5) & 7, b = blk >> 8;
    const int s0 = st * 64;
    const int sl = t >> 2, dh0 = (t & 3) * 32;
    const long row = (long)(b * SS) + s0 + sl;
    const float* g = gv_d + row * 32 + h * 4;
    float g0 = g[0], g1 = g[1], g2 = g[2], g3 = g[3];
    const short* va = v_all + row * 4096 + h * 512;
#pragma unroll
    for (int j = 0; j < 4; j++) {
        int dh = dh0 + j * 8;
        short8 e0 = *(const short8*)(va + 0 * 128 + dh);
        short8 e1 = *(const short8*)(va + 1 * 128 + dh);
        short8 e2 = *(const short8*)(va + 2 * 128 + dh);
        short8 e3 = *(const short8*)(va + 3 * 128 + dh);
        short8 outv;
#pragma unroll
        for (int i = 0; i < 8; i++)
            outv[i] = f2bf(g0 * b2f(e0[i]) + g1 * b2f(e1[i])
                         + g2 * b2f(e2[i]) + g3 * b2f(e3[i]));
        *(short8*)&Ls[sl * 136 + dh] = outv;
    }
    __syncthreads();
    const int dh = t >> 1, sc0 = (t & 1) * 32;
    short* op = Vt + ((long)(b * HH + h) * DHH + dh) * SS + s0 + sc0;
#pragma unroll
    for (int j = 0; j < 4; j++) {
        short8 ov;
#pragma unroll
        for (int i = 0; i < 8; i++)
            ov[i] = Ls[(sc0 + j * 8 + i) * 136 + dh];
        *(short8*)(op + j * 8) = ov;
    }
}

// ---------------------------------------------------------------------------
// MFMA flash attention v6 = R4's verified data path (register prefetch +
// explicit XOR-swizzled ds_writes, 512 blocks x 4 waves, 16 q/wave, 40 KB
// LDS) + three data-path-neutral tweaks:
//   - exp2 softmax (scale folded into Q/K projection; validated R5/R6)
//   - XCD-aware bijective block swizzle (512 = 8 x 64): blocks sharing
//     (b,h) K/V panels land on one XCD's L2
//   - s_setprio(1) around the MFMA/softmax region (T5)
// ---------------------------------------------------------------------------
#define NEG10L2E -14.426950408889634f
__global__ __launch_bounds__(256)
void shc_attn_mfma(const short* __restrict__ Q, const short* __restrict__ Kg,
                   const short* __restrict__ Vt, const float* __restrict__ go_d,
                   short* __restrict__ X)
{
    __shared__ __align__(16) char smem[40960];
    short* Ks = (short*)smem;                  // [64][128] shorts, swizzled (16384 B)
    short* Vs = (short*)(smem + 16384);        // [128][64] shorts, swizzled (16384 B)
    const int t = threadIdx.x;
    const int lane = t & 63, wave = t >> 6;
    const int lm = lane & 15, quad = lane >> 4;
    short* Pw = (short*)(smem + 32768) + wave * 16 * 64;  // per-wave [16][64] (2048 B)
    // XCD swizzle: bid 0..511, 8 XCDs -> blk = (bid%8)*64 + bid/8 (bijective)
    const int bid = blockIdx.x;
    const int blk = ((bid & 7) << 6) | (bid >> 3);
    const int qt = blk & 31, h = (blk >> 5) & 7, b = blk >> 8;
    const int q0 = qt * 64 + wave * 16;
    const short* Qb = Q + ((long)(b * SS) + q0) * DD + h * DHH;
    const short* Kb = Kg + (long)(b * SS) * DD + h * DHH;
    const short* Vb = Vt + (long)(b * HH + h) * DHH * SS;

    short8 af[4];
#pragma unroll
    for (int c = 0; c < 4; c++)
        af[c] = *(const short8*)(Qb + (long)lm * DD + c * 32 + quad * 8);

    f32x4 o_acc[8] = {};
    float l_lane[4] = {0.f, 0.f, 0.f, 0.f};

    const int ksrow = t >> 2, kscol = (t & 3) * 32;
    const int vsrow = t >> 1, vscol = (t & 1) * 32;
    const int kswz = (ksrow & 7) << 3;         // staging-write swizzles (shorts)
    const int vswz = (vsrow & 7) << 3;
    const int lmswz = (lm & 7) << 3;           // read-side swizzle (rows ≡ lm mod 8)

    // T14 prefetch: registers hold tile kt's data entering iteration kt
    short8 kv[4], vv[4];
#pragma unroll
    for (int j = 0; j < 4; j++) {
        kv[j] = *(const short8*)(Kb + (long)ksrow * DD + kscol + j * 8);
        vv[j] = *(const short8*)(Vb + (long)vsrow * SS + vscol + j * 8);
    }

    for (int kt = 0; kt < SS / 64; ++kt) {
        __syncthreads();                       // prev tile's reads done
#pragma unroll
        for (int j = 0; j < 4; j++) {
            *(short8*)&Ks[ksrow * 128 + ((kscol + j * 8) ^ kswz)] = kv[j];
            *(short8*)&Vs[vsrow * 64  + ((vscol + j * 8) ^ vswz)] = vv[j];
        }
        __syncthreads();

        // issue next tile's global loads now; they complete under compute
        const int ktn = (kt + 1) & 31;         // last iter: reload same (in-bounds, unused)
#pragma unroll
        for (int j = 0; j < 4; j++) {
            kv[j] = *(const short8*)(Kb + (long)(ktn * 64 + ksrow) * DD + kscol + j * 8);
            vv[j] = *(const short8*)(Vb + (long)vsrow * SS + ktn * 64 + vscol + j * 8);
        }

        __builtin_amdgcn_s_setprio(1);
        // QK^T: acc = (s - 10)*log2e; p = exp2(acc)
#pragma unroll
        for (int f = 0; f < 4; f++) {
            f32x4 acc = {NEG10L2E, NEG10L2E, NEG10L2E, NEG10L2E};
#pragma unroll
            for (int c = 0; c < 4; c++) {
                short8 bf = *(const short8*)&Ks[(f * 16 + lm) * 128
                                                + ((c * 32 + quad * 8) ^ lmswz)];
                acc = __builtin_amdgcn_mfma_f32_16x16x32_bf16(af[c], bf, acc, 0, 0, 0);
            }
#pragma unroll
            for (int r = 0; r < 4; r++) {
                float p = exp2f(acc[r]);
                l_lane[r] += p;
                const int pr = quad * 4 + r;
                Pw[pr * 64 + ((f * 16 + lm) ^ ((pr & 7) << 3))] = f2bf(p);
            }
        }

        short8 ap0 = *(const short8*)&Pw[lm * 64 + ((quad * 8) ^ lmswz)];
        short8 ap1 = *(const short8*)&Pw[lm * 64 + ((32 + quad * 8) ^ lmswz)];
#pragma unroll
        for (int d = 0; d < 8; d++) {
            short8 bv0 = *(const short8*)&Vs[(d * 16 + lm) * 64 + ((quad * 8) ^ lmswz)];
            short8 bv1 = *(const short8*)&Vs[(d * 16 + lm) * 64 + ((32 + quad * 8) ^ lmswz)];
            o_acc[d] = __builtin_amdgcn_mfma_f32_16x16x32_bf16(ap0, bv0, o_acc[d], 0, 0, 0);
            o_acc[d] = __builtin_amdgcn_mfma_f32_16x16x32_bf16(ap1, bv1, o_acc[d], 0, 0, 0);
        }
        __builtin_amdgcn_s_setprio(0);
    }

    float inv_r[4];
#pragma unroll
    for (int r = 0; r < 4; r++) {
        float l = l_lane[r];
        l += __shfl_xor(l, 1);
        l += __shfl_xor(l, 2);
        l += __shfl_xor(l, 4);
        l += __shfl_xor(l, 8);
        inv_r[r] = 1.f / l;
    }

    // Epilogue: o -> LDS (f32, row stride 132) -> gated X
    __syncthreads();                     // all waves done with Ks/Vs/Pw
    float* Of = (float*)smem;            // 64 rows * 132 f32 = 33792 B
#pragma unroll
    for (int r = 0; r < 4; r++) {
#pragma unroll
        for (int d = 0; d < 8; d++)
            Of[(wave * 16 + quad * 4 + r) * 132 + d * 16 + lm] = o_acc[d][r] * inv_r[r];
    }
    __syncthreads();
    const int xr = t >> 2, xc0 = (t & 3) * 8;
    const long grow = (long)(b * SS) + qt * 64 + xr;
    const float* go4 = go_d + grow * 32 + h * 4;
    float gg[4] = {go4[0], go4[1], go4[2], go4[3]};
    short* Xp = X + grow * 4096 + h * 512;
#pragma unroll
    for (int e = 0; e < 4; e++) {
#pragma unroll
        for (int j = 0; j < 4; j++) {
            int c = xc0 + 32 * j;
            f32x4 f0 = *(const f32x4*)&Of[xr * 132 + c];
            f32x4 f1 = *(const f32x4*)&Of[xr * 132 + c + 4];
            short8 s;
#pragma unroll
            for (int i = 0; i < 4; i++) {
                s[i]     = f2bf(f0[i] * gg[e]);
                s[4 + i] = f2bf(f1[i] * gg[e]);
            }
            *(short8*)(Xp + e * 128 + c) = s;
        }
    }
}

// ---------------------------------------------------------------------------
extern "C" void kernel_launch(void* const* d_in, const int* in_sizes, int n_in,
                              void* d_out, int out_size, void* d_ws, size_t ws_size,
                              hipStream_t stream)
{
    const float* q_src = (const float*)d_in[0];
    const float* k_src = (const float*)d_in[1];
    const float* v_src = (const float*)d_in[2];
    const float* Wq    = (const float*)d_in[3];
    const float* Wk    = (const float*)d_in[4];
    const float* Wv    = (const float*)d_in[5];
    const float* Wo    = (const float*)d_in[6];
    const float* sel_v = (const float*)d_in[7];
    const float* sel_o = (const float*)d_in[8];
    float* out = (float*)d_out;
    char* ws = (char*)d_ws;

    // Workspace layout (bytes), with lifetime-disjoint aliases:
    //   Qs16/Ks16 live in P1's region  (P1 written at launch 7, reads of Qs/Ks end at launch 2)
    //   Vs16 lives in Vtg's region     (Vtg written at launch 5, Vs16 last read launch 4)
    //   Wq16/Wk16 live in Vall's head  (Vall written at launch 4, reads end at launch 2)
    short* Qb16 = (short*)(ws + 0);            // [4096][1024] bf16  8.4 MB
    short* Kb16 = (short*)(ws + 8388608);      // [4096][1024] bf16  8.4 MB
    short* Vtg  = (short*)(ws + 16777216);     // [16][128][2048] bf16 8.4 MB
    short* Vs16 = (short*)(ws + 16777216);     // alias Vtg (dead before combine)
    short* Vall = (short*)(ws + 25165824);     // [4096][4096] bf16 33.5 MB
    short* X    = (short*)(ws + 25165824);     // alias Vall
    short* Wq16 = (short*)(ws + 25165824);     // alias Vall head (dead before v_all GEMM)
    short* Wk16 = (short*)(ws + 27262976);     // alias Vall +2.1MB
    float* P1   = (float*)(ws + 58720256);     // [4096][1024] f32 16.8 MB
    short* Qs16 = (short*)(ws + 58720256);     // alias P1 (dead before gemm_out)
    short* Ks16 = (short*)(ws + 67108864);     // alias P1 +8.4MB
    short* WvT  = (short*)(ws + 75497472);     // [4096][1024] bf16 8.4 MB
    short* WoT  = (short*)(ws + 83886080);     // [1024][4096] bf16 8.4 MB
    float* GVd  = (float*)(ws + 92274688);     // [4096][32] f32
    float* GOd  = (float*)(ws + 92798976);     // [4096][32] f32
    // total ~93.3 MB

    // DH^-0.25 * sqrt(log2 e): folds softmax exp -> exp2 (native v_exp_f32)
    const float s_scale = 0.29730177875068026f * 1.2011224087864498f;

    dim3 blk(256);
    // 0. f32 -> bf16 conversions (q/k/v sources; Wq/Wk)
    shc_cvt3<<<dim3(2048, 1, 3), blk, 0, stream>>>(q_src, k_src, v_src, Qs16, Ks16, Vs16);
    shc_cvt3<<<dim3(512, 1, 2), blk, 0, stream>>>(Wq, Wk, Wk, Wq16, Wk16, Wk16);
    // 1. Q and K projections, batched in one launch
    shc_gemm_qk<<<dim3(8, 32, 2), blk, 0, stream>>>(Qs16, Ks16, Wq16, Wk16, Qb16, Kb16, s_scale);
    // 2. Router gates v4 (2 rows/wave, block-per-side for L1 W reuse)
    shc_gates4<<<1024, blk, 0, stream>>>(q_src, k_src, sel_v, sel_o, GVd, GOd);
    // 3. merged weight transposes (Wv + Wo)
    shc_transpose_w<<<8192, blk, 0, stream>>>(Wv, WvT, Wo, WoT);
    // 4. v_all GEMM, gated combine + transpose
    shc_gemm_bt16<<<dim3(32, 32), blk, 0, stream>>>(Vs16, WvT, Vall, 1024, 1024, 1024, 4096, 1.0f);
    shc_combine_vt<<<512, blk, 0, stream>>>(Vall, GVd, Vtg);
    // 5. MFMA flash attention v6 (R4 data path + exp2 + XCD swizzle + setprio)
    shc_attn_mfma<<<512, blk, 0, stream>>>(Qb16, Kb16, Vtg, GOd, X);
    // 6. final GEMM, split-K=2 (512 blocks), then partial reduce
    shc_gemm_out<<<dim3(8, 32, 2), blk, 0, stream>>>(X, WoT, out, P1);
    shc_add<<<4096, blk, 0, stream>>>(out, P1);
}